// Round 12
// baseline (163.609 us; speedup 1.0000x reference)
//
#include <hip/hip_runtime.h>
#include <hip/hip_bf16.h>

#define NCOLS 32768
#define NZ 64
#define NT 40
#define DTF 30.0f
#define GAMMAC 0.55f

typedef _Float16 f16;

// Cap the pre-RA scheduler's prefetch window (r4->r5 lesson).
#define SBAR() __builtin_amdgcn_sched_barrier(0)

// lane^1 within quad: u<->v (t<->s) partner
__device__ __forceinline__ float dpp1(float x) {
    return __int_as_float(__builtin_amdgcn_mov_dpp(__float_as_int(x), 0xB1, 0xF, 0xF, true));
}
// lane^2 within quad: top<->bottom half exchange
__device__ __forceinline__ float dpp2(float x) {
    return __int_as_float(__builtin_amdgcn_mov_dpp(__float_as_int(x), 0x4E, 0xF, 0xF, true));
}
__device__ __forceinline__ unsigned int packh2(float a, float b) {
    union { f16 h[2]; unsigned int u; } v;
    v.h[0] = (f16)a; v.h[1] = (f16)b; return v.u;
}
__device__ __forceinline__ unsigned short f16bits(float a) {
    union { f16 h; unsigned short u; } v; v.h = (f16)a; return v.u;
}

// v_fma_mix_f32: d = f32(a_f16) * b_f32 + c  -- kills all v_cvt_f32_f16 in
// the hot loop (r11 was VALU-issue-bound: ~650 ops/step; mix -> ~330).
__device__ __forceinline__ float mix_ll16(unsigned a, float b, unsigned c) {
    float d;                     // a: f16 lo, c: f16 lo
    asm("v_fma_mix_f32 %0, %1, %2, %3 op_sel_hi:[1,0,1]"
        : "=v"(d) : "v"(a), "v"(b), "v"(c));
    return d;
}
__device__ __forceinline__ float mix_lh16(unsigned a, float b, unsigned c) {
    float d;                     // a: f16 lo, c: f16 hi
    asm("v_fma_mix_f32 %0, %1, %2, %3 op_sel:[0,0,1] op_sel_hi:[1,0,1]"
        : "=v"(d) : "v"(a), "v"(b), "v"(c));
    return d;
}
__device__ __forceinline__ float mix_lo(unsigned a, float b, float c) {
    float d;                     // a: f16 lo, c: f32
    asm("v_fma_mix_f32 %0, %1, %2, %3 op_sel_hi:[1,0,0]"
        : "=v"(d) : "v"(a), "v"(b), "v"(c));
    return d;
}
__device__ __forceinline__ float mix_hi(unsigned a, float b, float c) {
    float d;                     // a: f16 hi, c: f32
    asm("v_fma_mix_f32 %0, %1, %2, %3 op_sel:[1,0,0] op_sel_hi:[1,0,0]"
        : "=v"(d) : "v"(a), "v"(b), "v"(c));
    return d;
}

// BABE Thomas (r9-r11 structure), r12 changes:
//  - v_fma_mix_f32 for all coefficient ops (no f16 cvts in the loop)
//  - alpha folded into stored hg (hg' = hg*alpha; u,v share alpha);
//    Coriolis m = fma(r, oth, own) with per-thread r = +-dtfc/coef (0 for ts)
//  - CP/FG widened to b128 = 8 levels per read: 16 ds ops/step (was 24)
__global__ __launch_bounds__(512, 2) void scm_kernel(
    const float* __restrict__ u0, const float* __restrict__ v0,
    const float* __restrict__ t0, const float* __restrict__ s0,
    const float* __restrict__ hz, const float* __restrict__ akv,
    const float* __restrict__ akt, const float* __restrict__ tfo,
    const float* __restrict__ sfo, const float* __restrict__ uss,
    const float* __restrict__ vss, const float* __restrict__ usb,
    const float* __restrict__ vsb, const float* __restrict__ fcor,
    float* __restrict__ out)
{
    __shared__ uint4 Wsh[8 * 256];    // [j4][slot] 4 levels (hg*a,-e) = 32KB
    __shared__ uint4 CP4sh[4 * 256];  // [j8][slot] 8 levels -cp|-eq   = 16KB
    __shared__ uint4 FG4sh[4 * 512];  // [j8][ltid] 8 levels fg        = 32KB

    const int ltid = threadIdx.x;
    const int cb   = ltid >> 3;            // column in block 0..63
    const int sub  = ltid & 7;
    const int f01  = sub & 1;              // 0: u/t   1: v/s
    const int half = (sub >> 1) & 1;       // 0: top(k=0..31) 1: bottom(63..32)
    const int pr   = sub >> 2;             // 0: uv (akv)  1: ts (akt)
    const int field = pr * 2 + f01;
    const int col  = blockIdx.x * 64 + cb;
    const int slot = (cb << 2) | (pr << 1) | half;   // 0..255 (f01 pair shares)

    const float* ak  = pr ? akt : akv;
    const float* st0 = (field == 0) ? u0 : (field == 1) ? v0
                     : (field == 2) ? t0 : s0;

    // Coriolis: alpha folded into W at build; r = beta/alpha per thread.
    float walpha = 1.0f, rcor = 0.0f, bndv = 0.0f;
    {
        float fc   = fcor[col];
        float dtfc = DTF * fc;
        float cff  = dtfc * dtfc;
        float cff1 = 1.0f / (1.0f + GAMMAC * GAMMAC * cff);
        float coefc = 1.0f - GAMMAC * (1.0f - GAMMAC) * cff;
        if (!pr) {
            walpha = cff1 * coefc;
            rcor   = (f01 ? -dtfc : dtfc) / coefc;
            bndv   = half ?  DTF * ((f01 ? vss : uss)[col])
                          : -DTF * ((f01 ? vsb : usb)[col]);
        }
    }

    const float* hzc = hz + (size_t)col * NZ;
    const float* akc = ak + (size_t)col * (NZ + 1);
    const float* frc = (f01 ? sfo : tfo) + (size_t)col * NZ;

    // ---- build: affine indexing, separate top/bottom loops ----
    float cpn_own = 0.0f;   // junction: top -cp[31], bottom -eq[32] (f32)
    {
        float chainprev = 0.f, carry = 0.f;
        float hk = hzc[half ? 63 : 0];
        uint4 wacc = {}; uint4 c8 = {}, f8 = {};
        #pragma unroll
        for (int j = 0; j < 32; ++j) {
            float hnx, adj, fgk;
            if (!half) {
                hnx = hzc[j + 1];
                adj = (-2.0f * DTF) * akc[j + 1] / (hk + hnx);
                fgk = pr ? (DTF * frc[j]) : ((j == 0) ? bndv : 0.0f);
            } else {
                hnx = hzc[62 - j];
                adj = (-2.0f * DTF) * akc[63 - j] / (hk + hnx);
                fgk = pr ? (DTF * frc[63 - j]) : ((j == 0) ? bndv : 0.0f);
            }
            float b   = hk - carry - adj;
            float g   = 1.0f / (b - carry * chainprev);
            fgk *= g;
            unsigned int   wv  = packh2(hk * g * walpha, -carry * g);
            float          cpn = -(adj * g);
            unsigned short cv  = f16bits(cpn);
            unsigned short fv  = f16bits(fgk);
            switch (j & 7) {
                case 0: wacc.x = wv; c8.x = cv; f8.x = fv; break;
                case 1: wacc.y = wv; c8.x |= ((unsigned)cv << 16);
                        f8.x |= ((unsigned)fv << 16); break;
                case 2: wacc.z = wv; c8.y = cv; f8.y = fv; break;
                case 3: wacc.w = wv; c8.y |= ((unsigned)cv << 16);
                        f8.y |= ((unsigned)fv << 16);
                        if (f01 == 0) Wsh[(j >> 2) * 256 + slot] = wacc;
                        break;
                case 4: wacc.x = wv; c8.z = cv; f8.z = fv; break;
                case 5: wacc.y = wv; c8.z |= ((unsigned)cv << 16);
                        f8.z |= ((unsigned)fv << 16); break;
                case 6: wacc.z = wv; c8.w = cv; f8.w = fv; break;
                default:
                    wacc.w = wv; c8.w |= ((unsigned)cv << 16);
                    f8.w |= ((unsigned)fv << 16);
                    if (f01 == 0) {
                        Wsh[(j >> 2) * 256 + slot]   = wacc;
                        CP4sh[(j >> 3) * 256 + slot] = c8;
                    }
                    FG4sh[(j >> 3) * 512 + ltid] = f8;
                    break;
            }
            if (j == 31) cpn_own = cpn;
            chainprev = adj * g; carry = adj; hk = hnx;
            if ((j & 15) == 15) SBAR();
        }
    }

    // junction constants: s = 1/(1 - cp31*eq32)
    float cpn_oth = dpp2(cpn_own);
    float cptop   = half ? cpn_oth : cpn_own;
    float cpbot   = half ? cpn_own : cpn_oth;
    float smid    = 1.0f / (1.0f - cptop * cpbot);

    // ---- load state (local order; bottom reversed) ----
    float tau[32];
    {
        const float4* sp = (const float4*)(st0 + (size_t)col * NZ);
        if (!half) {
            #pragma unroll
            for (int q = 0; q < 8; ++q) {
                float4 v = sp[q];
                tau[4*q+0] = v.x; tau[4*q+1] = v.y;
                tau[4*q+2] = v.z; tau[4*q+3] = v.w;
            }
        } else {
            #pragma unroll
            for (int q = 0; q < 8; ++q) {
                float4 v = sp[15 - q];
                tau[4*q+0] = v.w; tau[4*q+1] = v.z;
                tau[4*q+2] = v.y; tau[4*q+3] = v.x;
            }
        }
    }

    // deviation shift for t,s (solve conserves constants)
    float meanadd = 0.0f;
    {
        float ss = 0.f;
        #pragma unroll
        for (int j = 0; j < 32; ++j) ss += tau[j];
        float tot = ss + dpp2(ss);
        if (pr) {
            meanadd = tot * (1.0f / 64.0f);
            #pragma unroll
            for (int j = 0; j < 32; ++j) tau[j] -= meanadd;
        }
    }

    __syncthreads();   // coefficients published; LDS read-only from here on

    // ---- 40 time steps ----
    for (int n = 0; n < NT; ++n) {
        // elimination sweep toward junction: dp = hg'*m + fg - e*dpprev
        float dpprev = 0.f;
        uint4 f8 = FG4sh[ltid];
        #pragma unroll
        for (int q = 0; q < 8; ++q) {
            uint4 w = Wsh[q * 256 + slot];
            if (q == 2 || q == 4 || q == 6) f8 = FG4sh[(q >> 1) * 512 + ltid];
            #pragma unroll
            for (int i = 0; i < 4; ++i) {
                const int j = 4*q + i;
                unsigned wv = (i == 0) ? w.x : (i == 1) ? w.y
                            : (i == 2) ? w.z : w.w;
                const int fc_ = (j & 7) >> 1;
                unsigned fgw = (fc_ == 0) ? f8.x : (fc_ == 1) ? f8.y
                             : (fc_ == 2) ? f8.z : f8.w;
                float own = tau[j];
                float oth = dpp1(own);                 // u<->v partner
                float m   = fmaf(rcor, oth, own);      // ts: rcor=0 -> own
                float t   = (j & 1) ? mix_lh16(wv, m, fgw)
                                    : mix_ll16(wv, m, fgw);
                float dp  = mix_hi(wv, dpprev, t);     // - e*dpprev + t
                tau[j] = dp;
                dpprev = dp;
            }
            if ((q & 3) == 3) SBAR();
        }
        // junction 2x2
        float other = dpp2(dpprev);
        float dtp = half ? other : dpprev;    // dp31
        float dbt = half ? dpprev : other;    // dq32
        float x31 = smid * fmaf(cptop, dbt, dtp);
        float xj  = half ? fmaf(cpn_own, x31, dpprev) : x31;
        tau[31] = xj;
        // substitution outward: x = cp*xn + dp
        float xn = xj;
        #pragma unroll
        for (int qq = 3; qq >= 0; --qq) {
            uint4 c8 = CP4sh[qq * 256 + slot];
            #pragma unroll
            for (int i = 7; i >= 0; --i) {
                const int j = 8*qq + i;
                if (j == 31) continue;        // junction already solved
                unsigned cw = ((i >> 1) == 0) ? c8.x : ((i >> 1) == 1) ? c8.y
                            : ((i >> 1) == 2) ? c8.z : c8.w;
                float x = (i & 1) ? mix_hi(cw, xn, tau[j])
                                  : mix_lo(cw, xn, tau[j]);
                tau[j] = x;
                xn = x;
            }
            if ((qq & 1) == 0) SBAR();
        }
    }

    // ---- store f32 output: out[field][col][k] (bottom reversed) ----
    float* op = out + ((size_t)field * NCOLS + col) * NZ;
    if (!half) {
        #pragma unroll
        for (int q = 0; q < 8; ++q) {
            float4 w;
            w.x = tau[4*q+0] + meanadd; w.y = tau[4*q+1] + meanadd;
            w.z = tau[4*q+2] + meanadd; w.w = tau[4*q+3] + meanadd;
            ((float4*)op)[q] = w;
        }
    } else {
        #pragma unroll
        for (int q = 0; q < 8; ++q) {
            float4 w;
            w.x = tau[4*q+3] + meanadd; w.y = tau[4*q+2] + meanadd;
            w.z = tau[4*q+1] + meanadd; w.w = tau[4*q+0] + meanadd;
            ((float4*)op)[15 - q] = w;
        }
    }
}

extern "C" void kernel_launch(void* const* d_in, const int* in_sizes, int n_in,
                              void* d_out, int out_size, void* d_ws, size_t ws_size,
                              hipStream_t stream) {
    const float* u0   = (const float*)d_in[0];
    const float* v0   = (const float*)d_in[1];
    const float* t0   = (const float*)d_in[2];
    const float* s0   = (const float*)d_in[3];
    const float* hz   = (const float*)d_in[4];
    const float* akv  = (const float*)d_in[5];
    const float* akt  = (const float*)d_in[6];
    const float* tfo  = (const float*)d_in[7];
    const float* sfo  = (const float*)d_in[8];
    const float* uss  = (const float*)d_in[9];
    const float* vss  = (const float*)d_in[10];
    const float* usb  = (const float*)d_in[11];
    const float* vsb  = (const float*)d_in[12];
    const float* fcor = (const float*)d_in[13];

    scm_kernel<<<dim3(NCOLS / 64), dim3(512), 0, stream>>>(
        u0, v0, t0, s0, hz, akv, akt, tfo, sfo, uss, vss, usb, vsb, fcor,
        (float*)d_out);
}

// Round 13
// 87.359 us; speedup vs baseline: 1.8728x; 1.8728x over previous
//
#include <hip/hip_runtime.h>
#include <hip/hip_bf16.h>

#define NCOLS 32768
#define NZ 64
#define NT 40
#define DTF 30.0f
#define GAMMAC 0.55f

typedef _Float16 f16;

// Cap the pre-RA scheduler's prefetch window (r4->r5: removed ~200MB of
// scratch-spill HBM traffic caused by hoisted ds_read live ranges).
#define SBAR() __builtin_amdgcn_sched_barrier(0)

// swap lanes (0,1) and (2,3) within each quad: u<->v, t<->s
__device__ __forceinline__ float dpp_swap1(float x) {
    return __int_as_float(__builtin_amdgcn_mov_dpp(__float_as_int(x), 0xB1, 0xF, 0xF, true));
}
__device__ __forceinline__ unsigned int packh2(float a, float b) {
    union { f16 h[2]; unsigned int u; } v;
    v.h[0] = (f16)a; v.h[1] = (f16)b; return v.u;
}
__device__ __forceinline__ unsigned short f16bits(float a) {
    union { f16 h; unsigned short u; } v; v.h = (f16)a; return v.u;
}
__device__ __forceinline__ float lo16f(unsigned int x) {
    union { unsigned int u; f16 h[2]; } v; v.u = x; return (float)v.h[0];
}
__device__ __forceinline__ float hi16f(unsigned int x) {
    union { unsigned int u; f16 h[2]; } v; v.u = x; return (float)v.h[1];
}

// r13 = r7 (best measured: 126us, granted 88 VGPR, zero spill) + 3 safe cuts:
//  1) alpha folded into stored hg (hg' = hg*alpha); loop: m = fma(rcor,oth,own)
//     with rcor = +-dtfc/coef (0 for t,s). -64 v_mul per step.
//  2) CP/FG widened to b128 (8 levels/read): 48 -> 32 ds ops/step.
//  3) uv lanes' fr pointer aimed at hzc (was ghost-reading sfo/tfo, ~16MB).
// r12 lesson: NO inline asm (spilled); r9-r12 lesson: stay in the r7
// envelope {256 thr, 80KB LDS, launch_bounds(256,2)} that the allocator
// provably grants 88 VGPRs without spilling.
__global__ __launch_bounds__(256, 2) void scm_kernel(
    const float* __restrict__ u0, const float* __restrict__ v0,
    const float* __restrict__ t0, const float* __restrict__ s0,
    const float* __restrict__ hz, const float* __restrict__ akv,
    const float* __restrict__ akt, const float* __restrict__ tfo,
    const float* __restrict__ sfo, const float* __restrict__ uss,
    const float* __restrict__ vss, const float* __restrict__ usb,
    const float* __restrict__ vsb, const float* __restrict__ fcor,
    float* __restrict__ out)
{
    __shared__ uint4 Wsh[16 * 128];   // [k4][pair] 4 levels (hg*a,-e) = 32KB
    __shared__ uint4 CP4sh[8 * 128];  // [k8][pair] 8 levels -cp       = 16KB
    __shared__ uint4 FG4sh[8 * 256];  // [k8][thread] 8 levels fg      = 32KB

    const int ltid  = threadIdx.x;
    const int tid   = blockIdx.x * 256 + ltid;
    const int field = tid & 3;          // 0=u 1=v 2=t 3=s
    const int col   = tid >> 2;
    const int p     = ltid >> 1;        // pair: (u,v) share akv, (t,s) share akt

    const float* ak  = (field < 2) ? akv : akt;
    const float* st0 = (field == 0) ? u0 : (field == 1) ? v0 : (field == 2) ? t0 : s0;

    // Coriolis: alpha folded into W at build; rcor = beta/alpha per thread.
    float walpha = 1.0f, rcor = 0.0f;
    {
        float fc   = fcor[col];
        float dtfc = DTF * fc;
        float cff  = dtfc * dtfc;
        float cff1 = 1.0f / (1.0f + GAMMAC * GAMMAC * cff);
        float coefc = 1.0f - GAMMAC * (1.0f - GAMMAC) * cff;
        if (field == 0)      { walpha = cff1 * coefc; rcor =  dtfc / coefc; }
        else if (field == 1) { walpha = cff1 * coefc; rcor = -dtfc / coefc; }
    }

    float bnd0 = 0.f, bnd63 = 0.f;
    if (field == 0)      { bnd0 = -DTF * usb[col]; bnd63 = DTF * uss[col]; }
    else if (field == 1) { bnd0 = -DTF * vsb[col]; bnd63 = DTF * vss[col]; }

    const float* hzc = hz + (size_t)col * NZ;
    const float* akc = ak + (size_t)col * (NZ + 1);
    // uv lanes: fr points at hzc (cheap L1 hits) instead of ghost-reading
    // tfo/sfo through the per-lane select. Value unused for uv.
    const float* fr  = (field >= 2) ? (((field == 2) ? tfo : sfo) + (size_t)col * NZ)
                                    : hzc;

    // ---- build folded Thomas coefficients, streamed, 4/8-level packed ----
    // a[k] = -2dt*ak[k]/(hz[k-1]+hz[k]); c[k]=a[k+1]; b[k]=hz[k]-a[k]-c[k]
    // g=1/(b-a*cp_prev); publish hg'=hz*g*alpha, e=a*g, cp=c*g, fg=rhs*g (f16)
    {
        float cpprev = 0.f, aik = 0.f, hk = hzc[0];
        uint4 wacc = {}; uint4 c8 = {}, f8 = {};
        #pragma unroll
        for (int k = 0; k < NZ; ++k) {
            float hk1 = 0.f, aik1 = 0.f;
            float frv = fr[k];
            if (k < NZ - 1) {
                hk1  = hzc[k + 1];
                aik1 = (-2.0f * DTF) * akc[k + 1] / (hk + hk1);
            }
            float bk    = hk - aik - aik1;
            float denom = bk - aik * cpprev;
            float g     = 1.0f / denom;
            float cpk   = aik1 * g;
            float fgk;
            if (field >= 2) fgk = (DTF * frv) * g;
            else            fgk = (k == 0 ? bnd0 : (k == NZ - 1 ? bnd63 : 0.0f)) * g;
            unsigned int   wv = packh2(hk * g * walpha, -aik * g);
            unsigned short cv = f16bits(-cpk);
            unsigned short fv = f16bits(fgk);
            switch (k & 7) {
                case 0: wacc.x = wv; c8.x = cv; f8.x = fv; break;
                case 1: wacc.y = wv; c8.x |= ((unsigned)cv << 16);
                        f8.x |= ((unsigned)fv << 16); break;
                case 2: wacc.z = wv; c8.y = cv; f8.y = fv; break;
                case 3: wacc.w = wv; c8.y |= ((unsigned)cv << 16);
                        f8.y |= ((unsigned)fv << 16);
                        if ((ltid & 1) == 0) Wsh[(k >> 2) * 128 + p] = wacc;
                        break;
                case 4: wacc.x = wv; c8.z = cv; f8.z = fv; break;
                case 5: wacc.y = wv; c8.z |= ((unsigned)cv << 16);
                        f8.z |= ((unsigned)fv << 16); break;
                case 6: wacc.z = wv; c8.w = cv; f8.w = fv; break;
                default:
                    wacc.w = wv; c8.w |= ((unsigned)cv << 16);
                    f8.w |= ((unsigned)fv << 16);
                    FG4sh[(k >> 3) * 256 + ltid] = f8;
                    if ((ltid & 1) == 0) {
                        Wsh[(k >> 2) * 128 + p]   = wacc;
                        CP4sh[(k >> 3) * 128 + p] = c8;
                    }
                    break;
            }
            cpprev = cpk; aik = aik1; hk = hk1;
            if ((k & 15) == 15) SBAR();
        }
    }

    // ---- load state ----
    float tau[NZ];
    {
        const float4* sp = (const float4*)(st0 + (size_t)col * NZ);
        #pragma unroll
        for (int k4 = 0; k4 < NZ / 4; ++k4) {
            float4 s = sp[k4];
            tau[4*k4+0] = s.x; tau[4*k4+1] = s.y;
            tau[4*k4+2] = s.z; tau[4*k4+3] = s.w;
        }
    }

    // deviation shift for t,s (solve conserves constants exactly): evolve
    // tau = state - mean, re-add at the end -> f16 coefficient rounding
    // cannot excite the conserved mode.
    float meanadd = 0.0f;
    if (field >= 2) {
        float ssum = 0.f;
        #pragma unroll
        for (int k = 0; k < NZ; ++k) ssum += tau[k];
        meanadd = ssum * (1.0f / NZ);
        #pragma unroll
        for (int k = 0; k < NZ; ++k) tau[k] -= meanadd;
    }

    __syncthreads();   // coefficients published; LDS read-only from here on

    // ---- 40 time steps: tau in regs, coefficients via wide LDS reads ----
    for (int n = 0; n < NT; ++n) {
        float dpprev = 0.f;
        uint4 f8;
        #pragma unroll
        for (int q = 0; q < 16; ++q) {
            uint4 w = Wsh[q * 128 + p];
            if ((q & 1) == 0) f8 = FG4sh[(q >> 1) * 256 + ltid];
            #pragma unroll
            for (int i = 0; i < 4; ++i) {
                unsigned wv = (i == 0) ? w.x : (i == 1) ? w.y
                            : (i == 2) ? w.z : w.w;
                const int sel = ((q & 1) << 1) | (i >> 1);
                unsigned fgw = (sel == 0) ? f8.x : (sel == 1) ? f8.y
                             : (sel == 2) ? f8.z : f8.w;
                float fgv = (i & 1) ? hi16f(fgw) : lo16f(fgw);
                float own = tau[4*q + i];
                float oth = dpp_swap1(own);             // u<->v partner
                float m   = fmaf(rcor, oth, own);       // ts: rcor=0 -> own
                float dp  = fmaf(lo16f(wv), m, fgv);    // hg'*m + fg
                dp = fmaf(hi16f(wv), dpprev, dp);       // - e*dp_prev
                tau[4*q + i] = dp;
                dpprev = dp;
            }
            if ((q & 3) == 3) SBAR();
        }
        float xn = 0.f;
        uint4 c8;
        #pragma unroll
        for (int q = 15; q >= 0; --q) {
            if ((q & 1) == 1) c8 = CP4sh[(q >> 1) * 128 + p];
            #pragma unroll
            for (int i = 3; i >= 0; --i) {
                const int sel = ((q & 1) << 1) | (i >> 1);
                unsigned cw = (sel == 0) ? c8.x : (sel == 1) ? c8.y
                            : (sel == 2) ? c8.z : c8.w;
                float cv = (i & 1) ? hi16f(cw) : lo16f(cw);
                float x = fmaf(cv, xn, tau[4*q + i]);   // dp - cp*x_next
                tau[4*q + i] = x;
                xn = x;
            }
            if ((q & 3) == 0) SBAR();
        }
    }

    // ---- store f32 output: out[field][col][k] ----
    float* op = out + ((size_t)field * NCOLS + col) * NZ;
    #pragma unroll
    for (int k4 = 0; k4 < NZ / 4; ++k4) {
        float4 w;
        w.x = tau[4*k4+0] + meanadd;
        w.y = tau[4*k4+1] + meanadd;
        w.z = tau[4*k4+2] + meanadd;
        w.w = tau[4*k4+3] + meanadd;
        ((float4*)op)[k4] = w;
    }
}

extern "C" void kernel_launch(void* const* d_in, const int* in_sizes, int n_in,
                              void* d_out, int out_size, void* d_ws, size_t ws_size,
                              hipStream_t stream) {
    const float* u0   = (const float*)d_in[0];
    const float* v0   = (const float*)d_in[1];
    const float* t0   = (const float*)d_in[2];
    const float* s0   = (const float*)d_in[3];
    const float* hz   = (const float*)d_in[4];
    const float* akv  = (const float*)d_in[5];
    const float* akt  = (const float*)d_in[6];
    const float* tfo  = (const float*)d_in[7];
    const float* sfo  = (const float*)d_in[8];
    const float* uss  = (const float*)d_in[9];
    const float* vss  = (const float*)d_in[10];
    const float* usb  = (const float*)d_in[11];
    const float* vsb  = (const float*)d_in[12];
    const float* fcor = (const float*)d_in[13];

    scm_kernel<<<dim3((NCOLS * 4) / 256), dim3(256), 0, stream>>>(
        u0, v0, t0, s0, hz, akv, akt, tfo, sfo, uss, vss, usb, vsb, fcor,
        (float*)d_out);
}